// Round 12
// baseline (3261.943 us; speedup 1.0000x reference)
//
#include <hip/hip_runtime.h>
#include <stdint.h>
#include <math.h>

#define N_ROWS 131072
#define K_CEN  2048
#define D_DIM  1024
#define BM     32
#define CSCALE 16.0f      // centroid pre-scale: lifts c out of e4m3 subnormal range
#define TAUS   6.5f       // scaled units; ~10 sigma of pairwise fp8 dot noise (validated R11)
#define CAND_CAP 32

typedef float f32x4  __attribute__((ext_vector_type(4)));
typedef int   i32x4  __attribute__((ext_vector_type(4)));

__device__ __forceinline__ unsigned f2ord(float f) {
  unsigned u = __float_as_uint(f);
  return (u & 0x80000000u) ? ~u : (u | 0x80000000u);  // monotone float->uint
}
__device__ __forceinline__ float ord2f(unsigned o) {
  unsigned u = (o & 0x80000000u) ? (o & 0x7fffffffu) : ~o;
  return __uint_as_float(u);
}
__device__ __forceinline__ unsigned pk4_fp8(float a0, float a1, float a2, float a3) {
  unsigned w = 0;
  w = __builtin_amdgcn_cvt_pk_fp8_f32(a0, a1, w, false);   // bytes 0,1
  w = __builtin_amdgcn_cvt_pk_fp8_f32(a2, a3, w, true);    // bytes 2,3
  return w;
}

// ---- prep: centroids fp32 -> fp8 e4m3 x CSCALE (row-major [K][D]) into ws (2 MB) ----
__global__ __launch_bounds__(256) void cvt_centroids(const float* __restrict__ cen,
                                                     unsigned* __restrict__ outb) {
  int i = blockIdx.x * 256 + threadIdx.x;           // 524288 threads x 4 floats -> 4 bytes
  float4 v = reinterpret_cast<const float4*>(cen)[i];
  outb[i] = pk4_fp8(v.x * CSCALE, v.y * CSCALE, v.z * CSCALE, v.w * CSCALE);
}

// ---- main: 256-thr WG (4 waves), BM=32, fp8. Registers engineered to the 3-waves/SIMD
// notch (<=85 VGPR: acc32+breg16+areg8+addr): occupancy model floor(256/VGPR) waves/SIMD
// (R8: 64->46%; R9/R11: 80-88 -> 1WG). LDS 39KB -> 3 WGs/CU. cenb 2MB L2-resident.
// Wave w owns cols [cb*256 + w*64 ..+64), tile 32x64, acc 2x4 of 16x16, 8 superblocks.
// R6-proven loop: depth-2 rotate B, per-ni interleave, 2 fences/iter, no setprio.
__global__ __launch_bounds__(256, 3) void assign_rows(
    const float* __restrict__ vec, const float* __restrict__ cenf,
    const unsigned char* __restrict__ cenb, int* __restrict__ out)
{
  __shared__ unsigned char v_lds[BM * D_DIM];       // 32 KB fp8, XOR-swizzled
  __shared__ unsigned rowmax_ord[BM];
  __shared__ int cand_cnt[BM];
  __shared__ unsigned candv[BM][CAND_CAP];          // fp8-dot score (ordered uint, scaled)
  __shared__ unsigned short candc[BM][CAND_CAP];    // centroid index

  const int tid  = threadIdx.x;
  const int lane = tid & 63;
  const int wid  = tid >> 6;     // 4 waves, each owns a 64-col strip per superblock
  const long row0 = (long)blockIdx.x * BM;

  if (tid < BM) { rowmax_ord[tid] = f2ord(-3.0e38f); cand_cnt[tid] = 0; }

  // stage v rows -> swizzled fp8 LDS (32 rows x 1024); nt loads (protect cenb in L2)
  #pragma unroll
  for (int it = 0; it < 8; ++it) {
    int cid = it * 256 + tid;          // 2048 chunks of 16 elems
    int r  = cid >> 6;                 // 64 chunks of 16 per row
    int dc = (cid & 63) << 4;
    const f32x4* vp = reinterpret_cast<const f32x4*>(vec + (row0 + r) * D_DIM + dc);
    f32x4 a = __builtin_nontemporal_load(vp);
    f32x4 b = __builtin_nontemporal_load(vp + 1);
    f32x4 c = __builtin_nontemporal_load(vp + 2);
    f32x4 d = __builtin_nontemporal_load(vp + 3);
    i32x4 pk;
    pk[0] = (int)pk4_fp8(a[0], a[1], a[2], a[3]);
    pk[1] = (int)pk4_fp8(b[0], b[1], b[2], b[3]);
    pk[2] = (int)pk4_fp8(c[0], c[1], c[2], c[3]);
    pk[3] = (int)pk4_fp8(d[0], d[1], d[2], d[3]);
    int byt = (r << 10) + dc;          // row stride 1024 B
    *reinterpret_cast<i32x4*>(reinterpret_cast<char*>(v_lds) + (byt ^ ((r & 7) << 4))) = pk;
  }
  __syncthreads();

  const int l15 = lane & 15;
  const int lq  = lane >> 4;
  const int amask = (l15 & 7) << 4;                 // lane-constant XOR swizzle (16B blocks)
  const int abase = (l15 << 10) + (lq << 3);        // row*1024B + k-octet*8B
  const char* v_bytes = reinterpret_cast<const char*>(v_lds);
  const char* c_bytes = reinterpret_cast<const char*>(cenb);

  for (int cb = 0; cb < 8; ++cb) {
    const int colbase = (cb << 8) + (wid << 6);     // 8 superblocks x 4 waves x 64 cols
    const size_t bbase = ((size_t)(colbase + l15) << 10) + (size_t)(lq << 3);
    const char* bp0 = c_bytes + bbase;              // per-ni bases, 16 cols = 16 KB apart
    const char* bp1 = bp0 + 16384;
    const char* bp2 = bp1 + 16384;
    const char* bp3 = bp2 + 16384;

    f32x4 acc[2][4];
    #pragma unroll
    for (int mi = 0; mi < 2; ++mi)
      #pragma unroll
      for (int ni = 0; ni < 4; ++ni) acc[mi][ni] = (f32x4){0.f,0.f,0.f,0.f};

    long breg[2][4];   // [k&1][ni] : depth-2 L2 prefetch (16 VGPR)
    long areg[2][2];   // [k&1][mi] : depth-2 LDS prefetch (8 VGPR)

    // prologue: B(k=0), B(k=1), A(k=0); fence pins these before the loop
    breg[0][0] = *reinterpret_cast<const long*>(bp0);
    breg[0][1] = *reinterpret_cast<const long*>(bp1);
    breg[0][2] = *reinterpret_cast<const long*>(bp2);
    breg[0][3] = *reinterpret_cast<const long*>(bp3);
    breg[1][0] = *reinterpret_cast<const long*>(bp0 + 32);
    breg[1][1] = *reinterpret_cast<const long*>(bp1 + 32);
    breg[1][2] = *reinterpret_cast<const long*>(bp2 + 32);
    breg[1][3] = *reinterpret_cast<const long*>(bp3 + 32);
    {
      int ta = abase ^ amask;
      areg[0][0] = *reinterpret_cast<const long*>(v_bytes + ta);
      areg[0][1] = *reinterpret_cast<const long*>(v_bytes + ta + 16384);
    }
    __builtin_amdgcn_sched_barrier(0);

    #pragma unroll
    for (int kc = 0; kc < 32; ++kc) {
      // phase 1: A(kc+1) from LDS (depth-1 ahead), ds_read_b64, 2-way (free) banks
      if (kc + 1 < 32) {
        int ta = (abase + ((kc + 1) << 5)) ^ amask;
        areg[(kc + 1) & 1][0] = *reinterpret_cast<const long*>(v_bytes + ta);
        areg[(kc + 1) & 1][1] = *reinterpret_cast<const long*>(v_bytes + ta + 16384);
      }
      __builtin_amdgcn_sched_barrier(0);
      // phase 2: 8 MFMA on A(kc),B(kc); B(kc+2) re-issued per-ni after its WAR clears.
      // Counted vmcnt (one younger iteration outstanding), never 0.
      #pragma unroll
      for (int ni = 0; ni < 4; ++ni) {
        #pragma unroll
        for (int mi = 0; mi < 2; ++mi)
          acc[mi][ni] = __builtin_amdgcn_mfma_f32_16x16x32_fp8_fp8(
              areg[kc & 1][mi], breg[kc & 1][ni], acc[mi][ni], 0, 0, 0);
        if (kc + 2 < 32) {
          const int ko = (kc + 2) << 5;
          const char* bp = ni==0?bp0: ni==1?bp1: ni==2?bp2: bp3;
          breg[kc & 1][ni] = *reinterpret_cast<const long*>(bp + ko);
        }
      }
      __builtin_amdgcn_sched_barrier(0);
    }

    // running row-max (C layout: col = l15, row = mi*16 + lq*4 + j) — scaled units
    #pragma unroll
    for (int mi = 0; mi < 2; ++mi) {
      #pragma unroll
      for (int j = 0; j < 4; ++j) {
        float mv = fmaxf(fmaxf(acc[mi][0][j], acc[mi][1][j]),
                         fmaxf(acc[mi][2][j], acc[mi][3][j]));
        mv = fmaxf(mv, __shfl_xor(mv, 1));
        mv = fmaxf(mv, __shfl_xor(mv, 2));
        mv = fmaxf(mv, __shfl_xor(mv, 4));
        mv = fmaxf(mv, __shfl_xor(mv, 8));
        if (l15 == 0) {
          int row = (mi << 4) + (lq << 2) + j;
          atomicMax(&rowmax_ord[row], f2ord(mv));
        }
      }
    }
    // all waves' maxima for this superblock included before appending (tight threshold;
    // still conservative: running max <= final max -> no true candidate missed)
    __syncthreads();
    #pragma unroll
    for (int mi = 0; mi < 2; ++mi) {
      #pragma unroll
      for (int j = 0; j < 4; ++j) {
        int row = (mi << 4) + (lq << 2) + j;
        float thr = ord2f(rowmax_ord[row]) - TAUS;
        #pragma unroll
        for (int ni = 0; ni < 4; ++ni) {
          float v = acc[mi][ni][j];
          if (v >= thr) {
            int slot = atomicAdd(&cand_cnt[row], 1);
            if (slot < CAND_CAP) {
              candv[row][slot] = f2ord(v);
              candc[row][slot] = (unsigned short)(colbase + (ni << 4) + l15);
            }
          }
        }
      }
    }
  }
  __syncthreads();

  // epilogue per row: overflow => exact full rescan; single survivor => direct out;
  // else exact fp64 rescore of survivors. First-occurrence (lowest col) tie-break.
  for (int r = wid; r < BM; r += 4) {
    const long grow = row0 + r;
    const int raw = cand_cnt[r];
    const float* vrow = vec + grow * D_DIM + (lane << 4);

    if (raw <= CAND_CAP) {
      const unsigned thro = f2ord(ord2f(rowmax_ord[r]) - TAUS);
      bool sv = (lane < raw) && (candv[r][lane] >= thro);
      unsigned long long bal = __ballot(sv);
      int nsurv = __popcll(bal);
      if (nsurv == 1) {
        int idx = __builtin_ctzll(bal);
        if (lane == 0) out[grow] = (int)candc[r][idx];
        continue;
      }
      float va[16];
      #pragma unroll
      for (int i = 0; i < 16; ++i) va[i] = vrow[i];
      double bestv = -1.0e300;
      int    besti = 0x7fffffff;
      for (int ci = 0; ci < raw; ++ci) {
        if (candv[r][ci] < thro) continue;
        const int col = (int)candc[r][ci];
        const float* crow = cenf + ((size_t)col << 10) + (lane << 4);
        double s = 0.0;
        #pragma unroll
        for (int i = 0; i < 16; ++i) s = fma((double)va[i], (double)crow[i], s);
        s += __shfl_xor(s, 32);
        s += __shfl_xor(s, 16);
        s += __shfl_xor(s, 8);
        s += __shfl_xor(s, 4);
        s += __shfl_xor(s, 2);
        s += __shfl_xor(s, 1);
        if (s > bestv || (s == bestv && col < besti)) { bestv = s; besti = col; }
      }
      if (lane == 0) out[grow] = besti;
    } else {
      // candidate list overflowed (P ~ 0): exact rescan of all K centroids
      float va[16];
      #pragma unroll
      for (int i = 0; i < 16; ++i) va[i] = vrow[i];
      double bestv = -1.0e300;
      int    besti = 0x7fffffff;
      for (int col = 0; col < K_CEN; ++col) {
        const float* crow = cenf + ((size_t)col << 10) + (lane << 4);
        double s = 0.0;
        #pragma unroll
        for (int i = 0; i < 16; ++i) s = fma((double)va[i], (double)crow[i], s);
        s += __shfl_xor(s, 32);
        s += __shfl_xor(s, 16);
        s += __shfl_xor(s, 8);
        s += __shfl_xor(s, 4);
        s += __shfl_xor(s, 2);
        s += __shfl_xor(s, 1);
        if (s > bestv) { bestv = s; besti = col; }
      }
      if (lane == 0) out[grow] = besti;
    }
  }
}

extern "C" void kernel_launch(void* const* d_in, const int* in_sizes, int n_in,
                              void* d_out, int out_size, void* d_ws, size_t ws_size,
                              hipStream_t stream) {
  const float* vec  = (const float*)d_in[0];   // [131072][1024] fp32
  const float* cenf = (const float*)d_in[1];   // [2048][1024] fp32 (pre-normalized)
  unsigned* cenb = (unsigned*)d_ws;            // 2 MB fp8 e4m3 centroids (x16 scaled)
  int* out = (int*)d_out;                      // [131072] int32 assignments

  cvt_centroids<<<(K_CEN * D_DIM / 4) / 256, 256, 0, stream>>>(cenf, cenb);
  assign_rows<<<N_ROWS / BM, 256, 0, stream>>>(vec, cenf,
                                               (const unsigned char*)cenb, out);
}

// Round 13
// 2007.249 us; speedup vs baseline: 1.6251x; 1.6251x over previous
//
#include <hip/hip_runtime.h>
#include <stdint.h>
#include <math.h>

#define N_ROWS 131072
#define K_CEN  2048
#define D_DIM  1024
#define BM     64
#define TAU    0.02f
#define CAND_CAP 64

typedef short bf16x8 __attribute__((ext_vector_type(8)));
typedef float f32x4  __attribute__((ext_vector_type(4)));

__device__ __forceinline__ unsigned short f2bf(float f) {
  unsigned u = __float_as_uint(f);
  return (unsigned short)((u + 0x7fffu + ((u >> 16) & 1u)) >> 16);  // RNE
}
__device__ __forceinline__ unsigned f2ord(float f) {
  unsigned u = __float_as_uint(f);
  return (u & 0x80000000u) ? ~u : (u | 0x80000000u);  // monotone float->uint
}
__device__ __forceinline__ float ord2f(unsigned o) {
  unsigned u = (o & 0x80000000u) ? (o & 0x7fffffffu) : ~o;
  return __uint_as_float(u);
}

// ---- prep: centroids fp32 -> bf16 (row-major [K][D]) into ws ----
__global__ __launch_bounds__(256) void cvt_centroids(const float* __restrict__ cen,
                                                     unsigned short* __restrict__ outb) {
  int i = blockIdx.x * 256 + threadIdx.x;           // 524288 threads x 4 floats
  float4 v = reinterpret_cast<const float4*>(cen)[i];
  ushort4 r;
  r.x = f2bf(v.x); r.y = f2bf(v.y); r.z = f2bf(v.z); r.w = f2bf(v.w);
  reinterpret_cast<ushort4*>(outb)[i] = r;
}

// ---- main: R6 structure at 16 waves. 1024-thr WG (16 waves = 4 waves/SIMD, forced:
// a 16-wave WG can only schedule at <=128 VGPR, so the RA must fit, no spill escape).
// Wave grid 2(wm) x 8(wn): tile 32 rows x 64 cols; wm-pairs share the same B stream
// (L1-hit for the second reader). A resident in LDS (128 KB bf16, XOR-swizzled);
// B streamed L2->regs depth-2 rotate with per-ni interleave (R6-proven). No setprio.
__global__ __launch_bounds__(1024, 1) void assign_rows(
    const float* __restrict__ vec, const float* __restrict__ cenf,
    const unsigned short* __restrict__ cenb, int* __restrict__ out)
{
  __shared__ unsigned short v_lds[BM * D_DIM];      // 128 KB, XOR-swizzled bf16
  __shared__ unsigned rowmax_ord[BM];
  __shared__ int cand_cnt[BM];
  __shared__ unsigned candv[BM][CAND_CAP];          // bf16-dot score (ordered uint)
  __shared__ unsigned short candc[BM][CAND_CAP];    // centroid index

  const int tid  = threadIdx.x;
  const int lane = tid & 63;
  const int wid  = tid >> 6;     // 16 waves
  const int wm   = wid >> 3;     // 0..1 : 32-row half
  const int wn   = wid & 7;      // 0..7 : 64-col strip within 512-col superblock
  const long row0 = (long)blockIdx.x * BM;

  if (tid < BM) { rowmax_ord[tid] = f2ord(-3.0e38f); cand_cnt[tid] = 0; }

  // stage v rows -> swizzled bf16 LDS (64 rows x 1024); nt (vec is stream-once)
  #pragma unroll
  for (int it = 0; it < 8; ++it) {
    int cid = it * 1024 + tid;
    int r  = cid >> 7;                 // 128 chunks of 8 per row
    int dc = (cid & 127) << 3;
    const f32x4* vp = reinterpret_cast<const f32x4*>(vec + (row0 + r) * D_DIM + dc);
    f32x4 a = __builtin_nontemporal_load(vp);
    f32x4 b = __builtin_nontemporal_load(vp + 1);
    bf16x8 pk;
    pk[0]=(short)f2bf(a[0]); pk[1]=(short)f2bf(a[1]); pk[2]=(short)f2bf(a[2]); pk[3]=(short)f2bf(a[3]);
    pk[4]=(short)f2bf(b[0]); pk[5]=(short)f2bf(b[1]); pk[6]=(short)f2bf(b[2]); pk[7]=(short)f2bf(b[3]);
    int byt = (r << 11) + (dc << 1);
    *reinterpret_cast<bf16x8*>(reinterpret_cast<char*>(v_lds) + (byt ^ ((r & 7) << 4))) = pk;
  }
  __syncthreads();

  const int l15 = lane & 15;
  const int lq  = lane >> 4;
  const int arow = (wm << 5) + l15;                 // A-fragment row for mi=0
  const int amask = (arow & 7) << 4;                // lane-constant XOR swizzle
  const int abase = (arow << 11) + (lq << 4);       // row*2048B + k-octet*16B
  const char* v_bytes = reinterpret_cast<const char*>(v_lds);
  const char* c_bytes = reinterpret_cast<const char*>(cenb);

  for (int cb = 0; cb < 4; ++cb) {
    const int colbase = (cb << 9) + (wn << 6);      // 4 superblocks x 8 strips x 64 cols
    const size_t bbase = ((size_t)(colbase + l15) << 11) + (size_t)(lq << 4);
    const char* bp0 = c_bytes + bbase;              // per-ni bases, 16 cols = 32 KB apart
    const char* bp1 = bp0 + 32768;
    const char* bp2 = bp1 + 32768;
    const char* bp3 = bp2 + 32768;

    f32x4 acc[2][4];
    #pragma unroll
    for (int mi = 0; mi < 2; ++mi)
      #pragma unroll
      for (int ni = 0; ni < 4; ++ni) acc[mi][ni] = (f32x4){0.f,0.f,0.f,0.f};

    bf16x8 breg[2][4];   // [k&1][ni] : depth-2 L2 prefetch (32 VGPR)
    bf16x8 areg[2][2];   // [k&1][mi] : depth-2 LDS prefetch (16 VGPR)

    // prologue: B(k=0), B(k=1), A(k=0); fence pins these before the loop
    breg[0][0] = *reinterpret_cast<const bf16x8*>(bp0);
    breg[0][1] = *reinterpret_cast<const bf16x8*>(bp1);
    breg[0][2] = *reinterpret_cast<const bf16x8*>(bp2);
    breg[0][3] = *reinterpret_cast<const bf16x8*>(bp3);
    breg[1][0] = *reinterpret_cast<const bf16x8*>(bp0 + 64);
    breg[1][1] = *reinterpret_cast<const bf16x8*>(bp1 + 64);
    breg[1][2] = *reinterpret_cast<const bf16x8*>(bp2 + 64);
    breg[1][3] = *reinterpret_cast<const bf16x8*>(bp3 + 64);
    {
      int ta = abase ^ amask;
      areg[0][0] = *reinterpret_cast<const bf16x8*>(v_bytes + ta);
      areg[0][1] = *reinterpret_cast<const bf16x8*>(v_bytes + ta + 32768);  // +16 rows
    }
    __builtin_amdgcn_sched_barrier(0);

    #pragma unroll
    for (int kc = 0; kc < 32; ++kc) {
      // phase 1: A(kc+1) from LDS (depth-1 ahead)
      if (kc + 1 < 32) {
        int ta = (abase + ((kc + 1) << 6)) ^ amask;
        areg[(kc + 1) & 1][0] = *reinterpret_cast<const bf16x8*>(v_bytes + ta);
        areg[(kc + 1) & 1][1] = *reinterpret_cast<const bf16x8*>(v_bytes + ta + 32768);
      }
      __builtin_amdgcn_sched_barrier(0);
      // phase 2: 8 MFMA on A(kc),B(kc); B(kc+2) re-issued per-ni after its WAR clears.
      // Counted vmcnt (one younger iteration outstanding), never 0.
      #pragma unroll
      for (int ni = 0; ni < 4; ++ni) {
        #pragma unroll
        for (int mi = 0; mi < 2; ++mi)
          acc[mi][ni] = __builtin_amdgcn_mfma_f32_16x16x32_bf16(
              areg[kc & 1][mi], breg[kc & 1][ni], acc[mi][ni], 0, 0, 0);
        if (kc + 2 < 32) {
          const int ko = (kc + 2) << 6;
          const char* bp = ni==0?bp0: ni==1?bp1: ni==2?bp2: bp3;
          breg[kc & 1][ni] = *reinterpret_cast<const bf16x8*>(bp + ko);
        }
      }
      __builtin_amdgcn_sched_barrier(0);
    }

    // running row-max (C layout: col = l15, row = wm*32 + mi*16 + lq*4 + j)
    #pragma unroll
    for (int mi = 0; mi < 2; ++mi) {
      #pragma unroll
      for (int j = 0; j < 4; ++j) {
        float mv = fmaxf(fmaxf(acc[mi][0][j], acc[mi][1][j]),
                         fmaxf(acc[mi][2][j], acc[mi][3][j]));
        mv = fmaxf(mv, __shfl_xor(mv, 1));
        mv = fmaxf(mv, __shfl_xor(mv, 2));
        mv = fmaxf(mv, __shfl_xor(mv, 4));
        mv = fmaxf(mv, __shfl_xor(mv, 8));
        if (l15 == 0) {
          int row = (wm << 5) + (mi << 4) + (lq << 2) + j;
          atomicMax(&rowmax_ord[row], f2ord(mv));
        }
      }
    }
    // include all 16 waves' maxima before appending (tight threshold; still
    // conservative: running max <= final max -> true argmax never missed)
    __syncthreads();
    #pragma unroll
    for (int mi = 0; mi < 2; ++mi) {
      #pragma unroll
      for (int j = 0; j < 4; ++j) {
        int row = (wm << 5) + (mi << 4) + (lq << 2) + j;
        float thr = ord2f(rowmax_ord[row]) - TAU;
        #pragma unroll
        for (int ni = 0; ni < 4; ++ni) {
          float v = acc[mi][ni][j];
          if (v >= thr) {
            int slot = atomicAdd(&cand_cnt[row], 1);
            if (slot < CAND_CAP) {
              candv[row][slot] = f2ord(v);
              candc[row][slot] = (unsigned short)(colbase + (ni << 4) + l15);
            }
          }
        }
      }
    }
  }
  __syncthreads();

  // epilogue per row: single fp8... (bf16) survivor => direct out; multiple => exact
  // fp64 rescore of survivors; overflow (P~0 at TAU=0.02) => full exact rescan.
  for (int r = wid; r < BM; r += 16) {
    const long grow = row0 + r;
    const int raw = cand_cnt[r];
    const float* vrow = vec + grow * D_DIM + (lane << 4);

    if (raw <= CAND_CAP) {
      const unsigned thro = f2ord(ord2f(rowmax_ord[r]) - TAU);
      bool sv = (lane < raw) && (candv[r][lane] >= thro);
      unsigned long long bal = __ballot(sv);
      int nsurv = __popcll(bal);
      if (nsurv == 1) {
        int idx = __builtin_ctzll(bal);
        if (lane == 0) out[grow] = (int)candc[r][idx];
        continue;
      }
      float va[16];
      #pragma unroll
      for (int i = 0; i < 16; ++i) va[i] = vrow[i];
      double bestv = -1.0e300;
      int    besti = 0x7fffffff;
      for (int ci = 0; ci < raw; ++ci) {
        if (candv[r][ci] < thro) continue;
        const int col = (int)candc[r][ci];
        const float* crow = cenf + ((size_t)col << 10) + (lane << 4);
        double s = 0.0;
        #pragma unroll
        for (int i = 0; i < 16; ++i) s = fma((double)va[i], (double)crow[i], s);
        s += __shfl_xor(s, 32);
        s += __shfl_xor(s, 16);
        s += __shfl_xor(s, 8);
        s += __shfl_xor(s, 4);
        s += __shfl_xor(s, 2);
        s += __shfl_xor(s, 1);
        if (s > bestv || (s == bestv && col < besti)) { bestv = s; besti = col; }
      }
      if (lane == 0) out[grow] = besti;
    } else {
      // candidate list overflowed: exact rescan of all K centroids
      float va[16];
      #pragma unroll
      for (int i = 0; i < 16; ++i) va[i] = vrow[i];
      double bestv = -1.0e300;
      int    besti = 0x7fffffff;
      for (int col = 0; col < K_CEN; ++col) {
        const float* crow = cenf + ((size_t)col << 10) + (lane << 4);
        double s = 0.0;
        #pragma unroll
        for (int i = 0; i < 16; ++i) s = fma((double)va[i], (double)crow[i], s);
        s += __shfl_xor(s, 32);
        s += __shfl_xor(s, 16);
        s += __shfl_xor(s, 8);
        s += __shfl_xor(s, 4);
        s += __shfl_xor(s, 2);
        s += __shfl_xor(s, 1);
        if (s > bestv) { bestv = s; besti = col; }
      }
      if (lane == 0) out[grow] = besti;
    }
  }
}

extern "C" void kernel_launch(void* const* d_in, const int* in_sizes, int n_in,
                              void* d_out, int out_size, void* d_ws, size_t ws_size,
                              hipStream_t stream) {
  const float* vec  = (const float*)d_in[0];   // [131072][1024] fp32
  const float* cenf = (const float*)d_in[1];   // [2048][1024] fp32 (pre-normalized)
  unsigned short* cenb = (unsigned short*)d_ws; // 4 MB bf16 centroids
  int* out = (int*)d_out;                      // [131072] int32 assignments

  cvt_centroids<<<(K_CEN * D_DIM / 4) / 256, 256, 0, stream>>>(cenf, cenb);
  assign_rows<<<N_ROWS / BM, 1024, 0, stream>>>(vec, cenf, cenb, out);
}